// Round 3
// baseline (502.210 us; speedup 1.0000x reference)
//
#include <hip/hip_runtime.h>
#include <hip/hip_cooperative_groups.h>
#include <math.h>

namespace cg = cooperative_groups;

#define NT 2560
#define DF 32
#define NB 4
#define SELF_EPS 0.5f
#define MS 8                 // m-split
#define MROWS (NT / MS)      // 320 m rows per unit
#define MT 64                // m tile
#define MITERS (MROWS / MT)  // 5
#define TN 64                // n rows per unit (4 waves x 16)
#define NBK (NT / TN)        // 40 n-blocks
#define GRID 1024            // 4 blocks/CU x 256 CU (co-resident, cooperative)
#define MAIN_UNITS (NBK * MS * NB)   // 1280
#define PREP_UNITS (NB * (NT / 32))  // 320
#define EPI_UNITS  (NB * (NT / 32))  // 320

typedef __attribute__((ext_vector_type(8))) short bf16x8;
typedef __attribute__((ext_vector_type(4))) float f32x4;

__device__ __forceinline__ unsigned short f2bf(float f) {
    unsigned u = __builtin_bit_cast(unsigned, f);
    u += 0x7fffu + ((u >> 16) & 1u);   // RNE
    return (unsigned short)(u >> 16);
}

__device__ __forceinline__ float fast_rcp(float x) {
#if __has_builtin(__builtin_amdgcn_rcpf)
    return __builtin_amdgcn_rcpf(x);
#else
    return 1.0f / x;
#endif
}

// tanh(relu(x)) = 1 - 2/(exp(2x)+1) for x>=0
__device__ __forceinline__ float tanh_relu(float x) {
    x = fmaxf(x, 0.0f);
    float e = __expf(x + x);
    return 1.0f - 2.0f * fast_rcp(e + 1.0f);
}

// shared-memory union: one allocation reused across phases
union LDSU {
    struct {
        unsigned short XmL[64 * 40];
        unsigned short HtL[32 * 72];
        unsigned short Ss[4 * 16 * 72];
    } m;                                        // 18944 B (main/agg)
    struct {
        float sW[32][33], sN[32][33];
        float sH[32][36], sA[32][36];
        float sT[32][33];
    } e;                                        // 21888 B (epilogue)
    float pT[32][33];                           // 4224 B (prep)
};

// ---------------------------------------------------------------------------
// unit bodies (shared by mega-kernel and fallback kernels)
// ---------------------------------------------------------------------------
__device__ __forceinline__ void prep_unit(
    LDSU& L, int t, int b, int n0,
    const float* __restrict__ X,
    unsigned short* __restrict__ Xb, unsigned short* __restrict__ XT)
{
    const int row = t >> 3, c4 = (t & 7) * 4;
    const size_t rbase = ((size_t)(b * NT + n0 + row)) * DF + c4;
    const float4 v = *(const float4*)(X + rbase);
    unsigned p0 = (unsigned)f2bf(v.x) | ((unsigned)f2bf(v.y) << 16);
    unsigned p1 = (unsigned)f2bf(v.z) | ((unsigned)f2bf(v.w) << 16);
    *(uint2*)(Xb + rbase) = make_uint2(p0, p1);
    L.pT[row][c4 + 0] = v.x; L.pT[row][c4 + 1] = v.y;
    L.pT[row][c4 + 2] = v.z; L.pT[row][c4 + 3] = v.w;
    __syncthreads();
    const int d = t >> 3, nq = (t & 7) * 4;
    unsigned q0 = (unsigned)f2bf(L.pT[nq + 0][d]) | ((unsigned)f2bf(L.pT[nq + 1][d]) << 16);
    unsigned q1 = (unsigned)f2bf(L.pT[nq + 2][d]) | ((unsigned)f2bf(L.pT[nq + 3][d]) << 16);
    *(uint2*)(XT + ((size_t)(b * DF + d)) * NT + n0 + nq) = make_uint2(q0, q1);
}

__device__ __forceinline__ void main_unit(
    LDSU& L, int t, int nb, int my, int b,
    const unsigned short* __restrict__ Xb, const unsigned short* __restrict__ HT,
    float* __restrict__ P, unsigned short* __restrict__ Sg)
{
    const int w = t >> 6, lane = t & 63;
    const int q = lane >> 4, c = lane & 15;
    const int n0 = nb * TN;
    const int mbase = my * MROWS;
    const size_t xbase = (size_t)b * NT * DF;
    const size_t tbase = (size_t)b * DF * NT;

    const bf16x8 bfn = *(const bf16x8*)(Xb + xbase + (size_t)(n0 + w * 16 + c) * DF + q * 8);

    f32x4 acc0 = {0.f, 0.f, 0.f, 0.f};
    f32x4 acc1 = {0.f, 0.f, 0.f, 0.f};

    const int xrow = t >> 2, xseg = t & 3;
    const int hrow = t >> 3, hseg = t & 7;

    uint4 xv = *(const uint4*)(Xb + xbase + (size_t)(mbase + xrow) * DF + xseg * 8);
    uint4 hv = *(const uint4*)(HT + tbase + (size_t)hrow * NT + mbase + hseg * 8);

    const int n_g = n0 + w * 16 + c;
    unsigned short* SsW = L.m.Ss + w * (16 * 72);
    unsigned short* Sgw = Sg
        + ((((size_t)b * MS + my) * NBK + nb) * 4 + w) * ((size_t)MITERS * 2 * 64 * 8)
        + (size_t)lane * 8;

    for (int it = 0; it < MITERS; ++it) {
        const int m0 = mbase + it * MT;
        __syncthreads();                       // prior LDS reads done
        *(uint4*)(L.m.XmL + xrow * 40 + xseg * 8) = xv;
        *(uint4*)(L.m.HtL + hrow * 72 + hseg * 8) = hv;
        if (it + 1 < MITERS) {
            const int m1 = m0 + MT;
            xv = *(const uint4*)(Xb + xbase + (size_t)(m1 + xrow) * DF + xseg * 8);
            hv = *(const uint4*)(HT + tbase + (size_t)hrow * NT + m1 + hseg * 8);
        }
        __syncthreads();                       // tiles staged

        if (m0 == n0) {
            #pragma unroll
            for (int t4 = 0; t4 < 4; ++t4) {
                const bf16x8 af = *(const bf16x8*)(L.m.XmL + (t4 * 16 + c) * 40 + q * 8);
                const f32x4 zero = {0.f, 0.f, 0.f, 0.f};
                f32x4 st = __builtin_amdgcn_mfma_f32_16x16x32_bf16(af, bfn, zero, 0, 0, 0);
                const int m2 = m0 + t4 * 16 + q * 4;
                float v0 = tanh_relu(st[0]); if (n_g == m2 + 0) v0 += SELF_EPS;
                float v1 = tanh_relu(st[1]); if (n_g == m2 + 1) v1 += SELF_EPS;
                float v2 = tanh_relu(st[2]); if (n_g == m2 + 2) v2 += SELF_EPS;
                float v3 = tanh_relu(st[3]); if (n_g == m2 + 3) v3 += SELF_EPS;
                unsigned p0 = (unsigned)f2bf(v0) | ((unsigned)f2bf(v1) << 16);
                unsigned p1 = (unsigned)f2bf(v2) | ((unsigned)f2bf(v3) << 16);
                *(uint2*)(SsW + c * 72 + t4 * 16 + q * 4) = make_uint2(p0, p1);
            }
        } else {
            #pragma unroll
            for (int t4 = 0; t4 < 4; ++t4) {
                const bf16x8 af = *(const bf16x8*)(L.m.XmL + (t4 * 16 + c) * 40 + q * 8);
                const f32x4 zero = {0.f, 0.f, 0.f, 0.f};
                f32x4 st = __builtin_amdgcn_mfma_f32_16x16x32_bf16(af, bfn, zero, 0, 0, 0);
                float v0 = tanh_relu(st[0]);
                float v1 = tanh_relu(st[1]);
                float v2 = tanh_relu(st[2]);
                float v3 = tanh_relu(st[3]);
                unsigned p0 = (unsigned)f2bf(v0) | ((unsigned)f2bf(v1) << 16);
                unsigned p1 = (unsigned)f2bf(v2) | ((unsigned)f2bf(v3) << 16);
                *(uint2*)(SsW + c * 72 + t4 * 16 + q * 4) = make_uint2(p0, p1);
            }
        }
        asm volatile("s_waitcnt lgkmcnt(0)" ::: "memory");

        #pragma unroll
        for (int kc = 0; kc < 2; ++kc) {
            const bf16x8 sf = *(const bf16x8*)(SsW + c * 72 + kc * 32 + q * 8);
            *(uint4*)(Sgw + (size_t)(it * 2 + kc) * (64 * 8)) = __builtin_bit_cast(uint4, sf);
            const bf16x8 h0 = *(const bf16x8*)(L.m.HtL + c * 72 + kc * 32 + q * 8);
            const bf16x8 h1 = *(const bf16x8*)(L.m.HtL + (16 + c) * 72 + kc * 32 + q * 8);
            acc0 = __builtin_amdgcn_mfma_f32_16x16x32_bf16(sf, h0, acc0, 0, 0, 0);
            acc1 = __builtin_amdgcn_mfma_f32_16x16x32_bf16(sf, h1, acc1, 0, 0, 0);
        }
    }

    float* ap = P + ((size_t)my * NB + b) * NT * DF + (size_t)(n0 + w * 16 + q * 4) * DF + c;
    #pragma unroll
    for (int r = 0; r < 4; ++r) {
        ap[(size_t)r * DF] = acc0[r];
        ap[(size_t)r * DF + 16] = acc1[r];
    }
}

__device__ __forceinline__ void agg_unit(
    LDSU& L, int t, int nb, int my, int b,
    const unsigned short* __restrict__ Sg, const unsigned short* __restrict__ HT,
    float* __restrict__ P)
{
    const int w = t >> 6, lane = t & 63;
    const int q = lane >> 4, c = lane & 15;
    const int n0 = nb * TN;
    const int mbase = my * MROWS;
    const size_t tbase = (size_t)b * DF * NT;

    const int hrow = t >> 3, hseg = t & 7;
    uint4 hv = *(const uint4*)(HT + tbase + (size_t)hrow * NT + mbase + hseg * 8);

    const unsigned short* Sp = Sg
        + ((((size_t)b * MS + my) * NBK + nb) * 4 + w) * ((size_t)MITERS * 2 * 64 * 8)
        + (size_t)lane * 8;

    bf16x8 sf0 = *(const bf16x8*)(Sp);
    bf16x8 sf1 = *(const bf16x8*)(Sp + 64 * 8);

    f32x4 acc0 = {0.f, 0.f, 0.f, 0.f};
    f32x4 acc1 = {0.f, 0.f, 0.f, 0.f};

    for (int it = 0; it < MITERS; ++it) {
        __syncthreads();                       // prior iter done reading HtL
        *(uint4*)(L.m.HtL + hrow * 72 + hseg * 8) = hv;
        bf16x8 nsf0, nsf1;
        if (it + 1 < MITERS) {
            hv = *(const uint4*)(HT + tbase + (size_t)hrow * NT
                                 + (mbase + (it + 1) * MT) + hseg * 8);
            nsf0 = *(const bf16x8*)(Sp + (size_t)((it + 1) * 2 + 0) * (64 * 8));
            nsf1 = *(const bf16x8*)(Sp + (size_t)((it + 1) * 2 + 1) * (64 * 8));
        }
        __syncthreads();                       // tile staged

        const bf16x8 h00 = *(const bf16x8*)(L.m.HtL + c * 72 + 0 * 32 + q * 8);
        const bf16x8 h01 = *(const bf16x8*)(L.m.HtL + (16 + c) * 72 + 0 * 32 + q * 8);
        acc0 = __builtin_amdgcn_mfma_f32_16x16x32_bf16(sf0, h00, acc0, 0, 0, 0);
        acc1 = __builtin_amdgcn_mfma_f32_16x16x32_bf16(sf0, h01, acc1, 0, 0, 0);
        const bf16x8 h10 = *(const bf16x8*)(L.m.HtL + c * 72 + 1 * 32 + q * 8);
        const bf16x8 h11 = *(const bf16x8*)(L.m.HtL + (16 + c) * 72 + 1 * 32 + q * 8);
        acc0 = __builtin_amdgcn_mfma_f32_16x16x32_bf16(sf1, h10, acc0, 0, 0, 0);
        acc1 = __builtin_amdgcn_mfma_f32_16x16x32_bf16(sf1, h11, acc1, 0, 0, 0);

        if (it + 1 < MITERS) { sf0 = nsf0; sf1 = nsf1; }
    }

    float* ap = P + ((size_t)my * NB + b) * NT * DF + (size_t)(n0 + w * 16 + q * 4) * DF + c;
    #pragma unroll
    for (int r = 0; r < 4; ++r) {
        ap[(size_t)r * DF] = acc0[r];
        ap[(size_t)r * DF + 16] = acc1[r];
    }
}

__device__ __forceinline__ void epi_unit(
    LDSU& L, int t, int b, int n0,
    const float* __restrict__ Hin, const float* __restrict__ P,
    const float* __restrict__ Wsl, const float* __restrict__ Wnl,
    const float* __restrict__ bl,
    float* __restrict__ Hout, unsigned short* __restrict__ HTout)
{
    const int row = t >> 3, c4 = (t & 7) * 4;
    const size_t rb = ((size_t)(b * NT + n0 + row)) * DF + c4;
    const float4 hv = *(const float4*)(Hin + rb);
    const size_t pstride = (size_t)NB * NT * DF;
    float4 av = *(const float4*)(P + rb);
    #pragma unroll
    for (int s = 1; s < MS; ++s) {
        const float4 pv = *(const float4*)(P + (size_t)s * pstride + rb);
        av.x += pv.x; av.y += pv.y; av.z += pv.z; av.w += pv.w;
    }
    const float4 w0 = *(const float4*)(Wsl + row * DF + c4);
    const float4 w1 = *(const float4*)(Wnl + row * DF + c4);
    L.e.sH[row][c4+0]=hv.x; L.e.sH[row][c4+1]=hv.y; L.e.sH[row][c4+2]=hv.z; L.e.sH[row][c4+3]=hv.w;
    L.e.sA[row][c4+0]=av.x; L.e.sA[row][c4+1]=av.y; L.e.sA[row][c4+2]=av.z; L.e.sA[row][c4+3]=av.w;
    L.e.sW[row][c4+0]=w0.x; L.e.sW[row][c4+1]=w0.y; L.e.sW[row][c4+2]=w0.z; L.e.sW[row][c4+3]=w0.w;
    L.e.sN[row][c4+0]=w1.x; L.e.sN[row][c4+1]=w1.y; L.e.sN[row][c4+2]=w1.z; L.e.sN[row][c4+3]=w1.w;
    __syncthreads();

    float4 z = make_float4(bl[c4+0], bl[c4+1], bl[c4+2], bl[c4+3]);
    #pragma unroll
    for (int k = 0; k < DF; ++k) {
        const float hk = L.e.sH[row][k], ak = L.e.sA[row][k];
        z.x += hk * L.e.sW[k][c4+0] + ak * L.e.sN[k][c4+0];
        z.y += hk * L.e.sW[k][c4+1] + ak * L.e.sN[k][c4+1];
        z.z += hk * L.e.sW[k][c4+2] + ak * L.e.sN[k][c4+2];
        z.w += hk * L.e.sW[k][c4+3] + ak * L.e.sN[k][c4+3];
    }
    z.x = z.x > 0.f ? z.x : __expf(z.x) - 1.f;
    z.y = z.y > 0.f ? z.y : __expf(z.y) - 1.f;
    z.z = z.z > 0.f ? z.z : __expf(z.z) - 1.f;
    z.w = z.w > 0.f ? z.w : __expf(z.w) - 1.f;
    *(float4*)(Hout + rb) = z;

    if (HTout != nullptr) {
        L.e.sT[row][c4+0]=z.x; L.e.sT[row][c4+1]=z.y; L.e.sT[row][c4+2]=z.z; L.e.sT[row][c4+3]=z.w;
        __syncthreads();
        const int d = t >> 3, nq = (t & 7) * 4;
        unsigned q0 = (unsigned)f2bf(L.e.sT[nq+0][d]) | ((unsigned)f2bf(L.e.sT[nq+1][d]) << 16);
        unsigned q1 = (unsigned)f2bf(L.e.sT[nq+2][d]) | ((unsigned)f2bf(L.e.sT[nq+3][d]) << 16);
        *(uint2*)(HTout + ((size_t)(b * DF + d)) * NT + n0 + nq) = make_uint2(q0, q1);
    }
}

// ---------------------------------------------------------------------------
// fused persistent cooperative kernel: prep -> main1 -> epi1 -> agg2 -> epi2
// ---------------------------------------------------------------------------
__global__ __launch_bounds__(256, 4)
void mega(const float* __restrict__ X, const float* __restrict__ Ws,
          const float* __restrict__ Wn, const float* __restrict__ bv,
          float* __restrict__ out, float* __restrict__ P, float* __restrict__ h1,
          unsigned short* __restrict__ Xb, unsigned short* __restrict__ XT,
          unsigned short* __restrict__ H1T, unsigned short* __restrict__ Sg)
{
    __shared__ LDSU L;
    cg::grid_group g = cg::this_grid();
    const int t = threadIdx.x;

    for (int u = blockIdx.x; u < PREP_UNITS; u += GRID) {
        prep_unit(L, t, u / 80, (u % 80) * 32, X, Xb, XT);
        __syncthreads();
    }
    g.sync();
    for (int u = blockIdx.x; u < MAIN_UNITS; u += GRID) {
        const int nb = u % NBK, r = u / NBK;
        main_unit(L, t, nb, r % MS, r / MS, Xb, XT, P, Sg);
    }
    g.sync();
    for (int u = blockIdx.x; u < EPI_UNITS; u += GRID) {
        epi_unit(L, t, u / 80, (u % 80) * 32, X, P, Ws, Wn, bv, h1, H1T);
        __syncthreads();
    }
    g.sync();
    for (int u = blockIdx.x; u < MAIN_UNITS; u += GRID) {
        const int nb = u % NBK, r = u / NBK;
        agg_unit(L, t, nb, r % MS, r / MS, Sg, H1T, P);
    }
    g.sync();
    for (int u = blockIdx.x; u < EPI_UNITS; u += GRID) {
        epi_unit(L, t, u / 80, (u % 80) * 32, h1, P, Ws + DF * DF, Wn + DF * DF,
                 bv + DF, out, nullptr);
        __syncthreads();
    }
}

// ---------------------------------------------------------------------------
// fallback kernels (R2-proven 5-dispatch path)
// ---------------------------------------------------------------------------
__global__ __launch_bounds__(256, 4)
void prep(const float* __restrict__ X,
          unsigned short* __restrict__ Xb, unsigned short* __restrict__ XT)
{
    __shared__ LDSU L;
    prep_unit(L, threadIdx.x, blockIdx.x / 80, (blockIdx.x % 80) * 32, X, Xb, XT);
}

__global__ __launch_bounds__(256, 4)
void gsage_main(const unsigned short* __restrict__ Xb,
                const unsigned short* __restrict__ HT,
                float* __restrict__ P, unsigned short* __restrict__ Sg)
{
    __shared__ LDSU L;
    main_unit(L, threadIdx.x, blockIdx.x, blockIdx.y, blockIdx.z, Xb, HT, P, Sg);
}

__global__ __launch_bounds__(256, 4)
void gsage_agg(const unsigned short* __restrict__ Sg,
               const unsigned short* __restrict__ HT, float* __restrict__ P)
{
    __shared__ LDSU L;
    agg_unit(L, threadIdx.x, blockIdx.x, blockIdx.y, blockIdx.z, Sg, HT, P);
}

__global__ __launch_bounds__(256, 4)
void gsage_epi(const float* __restrict__ Hin, const float* __restrict__ P,
               const float* __restrict__ Wsl, const float* __restrict__ Wnl,
               const float* __restrict__ bl,
               float* __restrict__ Hout, unsigned short* __restrict__ HTout)
{
    __shared__ LDSU L;
    epi_unit(L, threadIdx.x, blockIdx.y, blockIdx.x * 32, Hin, P, Wsl, Wnl, bl, Hout, HTout);
}

extern "C" void kernel_launch(void* const* d_in, const int* in_sizes, int n_in,
                              void* d_out, int out_size, void* d_ws, size_t ws_size,
                              hipStream_t stream) {
    const float* X  = (const float*)d_in[0];
    const float* Ws = (const float*)d_in[1];   // [2][32][32]
    const float* Wn = (const float*)d_in[2];   // [2][32][32]
    const float* bv = (const float*)d_in[3];   // [2][32]
    float* out = (float*)d_out;

    char* ws = (char*)d_ws;
    float* P  = (float*)ws;                                  // 10,485,760 B
    float* h1 = P + (size_t)MS * NB * NT * DF;               // 1,310,720 B
    unsigned short* Xb  = (unsigned short*)(ws + 11796480);  // 655,360 B
    unsigned short* XT  = Xb + (size_t)NB * NT * DF;         // 655,360 B
    unsigned short* H1T = XT + (size_t)NB * NT * DF;         // 655,360 B
    unsigned short* Sg  = H1T + (size_t)NB * NT * DF;        // 52,428,800 B

    void* kargs[] = { (void*)&X, (void*)&Ws, (void*)&Wn, (void*)&bv,
                      (void*)&out, (void*)&P, (void*)&h1,
                      (void*)&Xb, (void*)&XT, (void*)&H1T, (void*)&Sg };
    hipError_t err = hipLaunchCooperativeKernel(
        reinterpret_cast<const void*>(&mega), dim3(GRID), dim3(256), kargs, 0, stream);

    if (err != hipSuccess) {
        // fallback: proven 5-dispatch path
        prep<<<320, 256, 0, stream>>>(X, Xb, XT);
        dim3 gdim(NBK, MS, NB);
        gsage_main<<<gdim, 256, 0, stream>>>(Xb, XT, P, Sg);
        gsage_epi<<<dim3(NT / 32, NB), 256, 0, stream>>>(X, P, Ws, Wn, bv, h1, H1T);
        gsage_agg<<<gdim, 256, 0, stream>>>(Sg, H1T, P);
        gsage_epi<<<dim3(NT / 32, NB), 256, 0, stream>>>(h1, P, Ws + DF * DF,
                                                         Wn + DF * DF, bv + DF, out, nullptr);
    }
}

// Round 5
// 169.496 us; speedup vs baseline: 2.9630x; 2.9630x over previous
//
#include <hip/hip_runtime.h>
#include <math.h>

#define NT 2560
#define DF 32
#define NB 4
#define SELF_EPS 0.5f
#define WMS 4                   // m-split across waves WITHIN a block
#define MROWS (NT / WMS)        // 640 m rows per wave
#define MT 64                   // m tile per iter
#define MITERS (MROWS / MT)     // 10
#define TN 16                   // n rows per block
#define NBK (NT / TN)           // 160 n-blocks
#define SG_FRAG (MITERS * 2 * 64 * 8)   // 10240 shorts per (block,wave) stream

typedef __attribute__((ext_vector_type(8))) short bf16x8;
typedef __attribute__((ext_vector_type(4))) float f32x4;

__device__ __forceinline__ unsigned short f2bf(float f) {
    unsigned u = __builtin_bit_cast(unsigned, f);
    u += 0x7fffu + ((u >> 16) & 1u);   // RNE
    return (unsigned short)(u >> 16);
}

__device__ __forceinline__ float fast_rcp(float x) {
#if __has_builtin(__builtin_amdgcn_rcpf)
    return __builtin_amdgcn_rcpf(x);
#else
    return 1.0f / x;
#endif
}

// tanh(relu(x)) = 1 - 2/(exp(2x)+1) for x>=0
__device__ __forceinline__ float tanh_relu(float x) {
    x = fmaxf(x, 0.0f);
    float e = __expf(x + x);
    return 1.0f - 2.0f * fast_rcp(e + 1.0f);
}

// ---------------------------------------------------------------------------
// prep: X fp32 -> Xb bf16 row-major [B][NT][32] and XT bf16 [B][32][NT].
// ---------------------------------------------------------------------------
__global__ __launch_bounds__(256, 4)
void prep(const float* __restrict__ X,
          unsigned short* __restrict__ Xb, unsigned short* __restrict__ XT)
{
    const int t = threadIdx.x;
    __shared__ float sT[32][33];
    const int tile = blockIdx.x;
    const int b = tile / 80, n0 = (tile % 80) * 32;
    const int row = t >> 3, c4 = (t & 7) * 4;
    const size_t rbase = ((size_t)(b * NT + n0 + row)) * DF + c4;
    const float4 v = *(const float4*)(X + rbase);
    unsigned p0 = (unsigned)f2bf(v.x) | ((unsigned)f2bf(v.y) << 16);
    unsigned p1 = (unsigned)f2bf(v.z) | ((unsigned)f2bf(v.w) << 16);
    *(uint2*)(Xb + rbase) = make_uint2(p0, p1);
    sT[row][c4 + 0] = v.x; sT[row][c4 + 1] = v.y;
    sT[row][c4 + 2] = v.z; sT[row][c4 + 3] = v.w;
    __syncthreads();
    const int d = t >> 3, nq = (t & 7) * 4;
    unsigned q0 = (unsigned)f2bf(sT[nq + 0][d]) | ((unsigned)f2bf(sT[nq + 1][d]) << 16);
    unsigned q1 = (unsigned)f2bf(sT[nq + 2][d]) | ((unsigned)f2bf(sT[nq + 3][d]) << 16);
    *(uint2*)(XT + ((size_t)(b * DF + d)) * NT + n0 + nq) = make_uint2(q0, q1);
}

// ---------------------------------------------------------------------------
// K1 (layer 1, fully fused): block = 16 n-rows x full m (2560) x batch b.
// Wave w owns m-slice [w*640, w*640+640): barrier-free main loop on private
// LDS regions (wave-local lgkmcnt only). Then LDS-reduce the 4 wave partials
// and run the epilogue inline (elu(X*Ws + agg*Wn + b)), emitting h1 + H1T.
// A-layout score fragments are streamed to Sg for K2 (no layer-2 scores).
// ---------------------------------------------------------------------------
union K1LDS {
    struct {
        unsigned short Xm[WMS][64 * 40];   // per-wave m-tile, pad 40
        unsigned short Ht[WMS][32 * 72];   // per-wave H^T tile, pad 72
        unsigned short Ss[WMS][16 * 72];   // per-wave S round-trip
    } m;                                   // 48128 B
    struct {
        float red[WMS][16][32];            // wave partial aggs
        float sW[32][33], sN[32][33];
        float sH[16][33], sA[16][33], sT[16][33];
    } e;                                   // 22976 B
};

__global__ __launch_bounds__(256, 3)
void k1(const float* __restrict__ X,
        const unsigned short* __restrict__ Xb,
        const unsigned short* __restrict__ XT,
        const float* __restrict__ Wsl, const float* __restrict__ Wnl,
        const float* __restrict__ bl,
        float* __restrict__ h1, unsigned short* __restrict__ H1T,
        unsigned short* __restrict__ Sg)
{
    __shared__ K1LDS L;
    const int t = threadIdx.x;
    const int w = t >> 6, lane = t & 63;
    const int q = lane >> 4, c = lane & 15;
    const int nb = blockIdx.x, b = blockIdx.y;
    const int n0 = nb * TN;
    const size_t xbase = (size_t)b * NT * DF;
    const size_t tbase = (size_t)b * DF * NT;
    const int mw = w * MROWS;

    // score B-frag: the block's 16 n-rows (same for all waves)
    const bf16x8 bfn = *(const bf16x8*)(Xb + xbase + (size_t)(n0 + c) * DF + q * 8);

    const int xrow = lane >> 2, xseg = lane & 3;   // Xm: 16 rows x 4 segs per s
    const int hrow = lane >> 3, hseg = lane & 7;   // Ht: 8 d x 8 segs per s

    uint4 xv[4], hv[4];
#pragma unroll
    for (int s = 0; s < 4; ++s) {
        xv[s] = *(const uint4*)(Xb + xbase + (size_t)(mw + s * 16 + xrow) * DF + xseg * 8);
        hv[s] = *(const uint4*)(XT + tbase + (size_t)(s * 8 + hrow) * NT + mw + hseg * 8);
    }

    unsigned short* XmW = L.m.Xm[w];
    unsigned short* HtW = L.m.Ht[w];
    unsigned short* SsW = L.m.Ss[w];
    unsigned short* Sgw = Sg + (((size_t)b * NBK + nb) * WMS + w) * SG_FRAG
                        + (size_t)lane * 8;

    f32x4 acc0 = {0.f, 0.f, 0.f, 0.f};
    f32x4 acc1 = {0.f, 0.f, 0.f, 0.f};

    for (int it = 0; it < MITERS; ++it) {
        const int m0 = mw + it * MT;
        // wave-local: prior iter's LDS reads drained before overwrite
        asm volatile("s_waitcnt lgkmcnt(0)" ::: "memory");
#pragma unroll
        for (int s = 0; s < 4; ++s) {
            *(uint4*)(XmW + (s * 16 + xrow) * 40 + xseg * 8) = xv[s];
            *(uint4*)(HtW + (s * 8 + hrow) * 72 + hseg * 8) = hv[s];
        }
        if (it + 1 < MITERS) {
            const int m1 = m0 + MT;
#pragma unroll
            for (int s = 0; s < 4; ++s) {
                xv[s] = *(const uint4*)(Xb + xbase + (size_t)(m1 + s * 16 + xrow) * DF + xseg * 8);
                hv[s] = *(const uint4*)(XT + tbase + (size_t)(s * 8 + hrow) * NT + m1 + hseg * 8);
            }
        }
        asm volatile("s_waitcnt lgkmcnt(0)" ::: "memory");   // tiles staged (wave-local)

        // ---- scores: 4x (16m x 16n) tiles; lane holds S[n=c][m=t4*16+q*4+r]
#pragma unroll
        for (int t4 = 0; t4 < 4; ++t4) {
            const bf16x8 af = *(const bf16x8*)(XmW + (t4 * 16 + c) * 40 + q * 8);
            const f32x4 zero = {0.f, 0.f, 0.f, 0.f};
            f32x4 st = __builtin_amdgcn_mfma_f32_16x16x32_bf16(af, bfn, zero, 0, 0, 0);
            const int mt = m0 + t4 * 16;
            float v0 = tanh_relu(st[0]), v1 = tanh_relu(st[1]);
            float v2 = tanh_relu(st[2]), v3 = tanh_relu(st[3]);
            if ((unsigned)(n0 - mt) < 16u || (unsigned)(mt - n0) < 16u) {
                const int m2 = mt + q * 4, n_g = n0 + c;
                if (n_g == m2 + 0) v0 += SELF_EPS;
                if (n_g == m2 + 1) v1 += SELF_EPS;
                if (n_g == m2 + 2) v2 += SELF_EPS;
                if (n_g == m2 + 3) v3 += SELF_EPS;
            }
            unsigned p0 = (unsigned)f2bf(v0) | ((unsigned)f2bf(v1) << 16);
            unsigned p1 = (unsigned)f2bf(v2) | ((unsigned)f2bf(v3) << 16);
            *(uint2*)(SsW + c * 72 + t4 * 16 + q * 4) = make_uint2(p0, p1);
        }
        asm volatile("s_waitcnt lgkmcnt(0)" ::: "memory");

        // ---- agg: acc[n][d] += S[n][m] * H[m][d]; stream S-frags to Sg ----
#pragma unroll
        for (int kc = 0; kc < 2; ++kc) {
            const bf16x8 sf = *(const bf16x8*)(SsW + c * 72 + kc * 32 + q * 8);
            *(uint4*)(Sgw + (size_t)(it * 2 + kc) * (64 * 8)) = __builtin_bit_cast(uint4, sf);
            const bf16x8 hf0 = *(const bf16x8*)(HtW + c * 72 + kc * 32 + q * 8);
            const bf16x8 hf1 = *(const bf16x8*)(HtW + (16 + c) * 72 + kc * 32 + q * 8);
            acc0 = __builtin_amdgcn_mfma_f32_16x16x32_bf16(sf, hf0, acc0, 0, 0, 0);
            acc1 = __builtin_amdgcn_mfma_f32_16x16x32_bf16(sf, hf1, acc1, 0, 0, 0);
        }
    }

    // ---- in-block reduce of 4 wave partials + inline epilogue ----
    asm volatile("s_waitcnt lgkmcnt(0)" ::: "memory");
    __syncthreads();                       // all waves done with L.m (alias!)

#pragma unroll
    for (int r = 0; r < 4; ++r) {
        L.e.red[w][q * 4 + r][c]      = acc0[r];
        L.e.red[w][q * 4 + r][16 + c] = acc1[r];
    }
    const int row8 = t >> 3, c4 = (t & 7) * 4;
    {
        const float4 wv0 = *(const float4*)(Wsl + row8 * DF + c4);
        const float4 wv1 = *(const float4*)(Wnl + row8 * DF + c4);
        L.e.sW[row8][c4+0]=wv0.x; L.e.sW[row8][c4+1]=wv0.y;
        L.e.sW[row8][c4+2]=wv0.z; L.e.sW[row8][c4+3]=wv0.w;
        L.e.sN[row8][c4+0]=wv1.x; L.e.sN[row8][c4+1]=wv1.y;
        L.e.sN[row8][c4+2]=wv1.z; L.e.sN[row8][c4+3]=wv1.w;
    }
    float4 hvv;
    if (t < 128) {
        hvv = *(const float4*)(X + xbase + (size_t)(n0 + row8) * DF + c4);
    }
    __syncthreads();                       // red + weights visible
    if (t < 128) {
        float4 a = *(const float4*)&L.e.red[0][row8][c4];
#pragma unroll
        for (int ww = 1; ww < WMS; ++ww) {
            const float4 p = *(const float4*)&L.e.red[ww][row8][c4];
            a.x += p.x; a.y += p.y; a.z += p.z; a.w += p.w;
        }
        L.e.sA[row8][c4+0]=a.x; L.e.sA[row8][c4+1]=a.y;
        L.e.sA[row8][c4+2]=a.z; L.e.sA[row8][c4+3]=a.w;
        L.e.sH[row8][c4+0]=hvv.x; L.e.sH[row8][c4+1]=hvv.y;
        L.e.sH[row8][c4+2]=hvv.z; L.e.sH[row8][c4+3]=hvv.w;
    }
    __syncthreads();
    if (t < 128) {
        float4 z = make_float4(bl[c4+0], bl[c4+1], bl[c4+2], bl[c4+3]);
#pragma unroll
        for (int k = 0; k < DF; ++k) {
            const float hk = L.e.sH[row8][k], ak = L.e.sA[row8][k];
            z.x += hk * L.e.sW[k][c4+0] + ak * L.e.sN[k][c4+0];
            z.y += hk * L.e.sW[k][c4+1] + ak * L.e.sN[k][c4+1];
            z.z += hk * L.e.sW[k][c4+2] + ak * L.e.sN[k][c4+2];
            z.w += hk * L.e.sW[k][c4+3] + ak * L.e.sN[k][c4+3];
        }
        z.x = z.x > 0.f ? z.x : __expf(z.x) - 1.f;
        z.y = z.y > 0.f ? z.y : __expf(z.y) - 1.f;
        z.z = z.z > 0.f ? z.z : __expf(z.z) - 1.f;
        z.w = z.w > 0.f ? z.w : __expf(z.w) - 1.f;
        *(float4*)(h1 + xbase + (size_t)(n0 + row8) * DF + c4) = z;
        L.e.sT[row8][c4+0]=z.x; L.e.sT[row8][c4+1]=z.y;
        L.e.sT[row8][c4+2]=z.z; L.e.sT[row8][c4+3]=z.w;
    }
    __syncthreads();
    if (t < 128) {                          // H1T: [B][32][NT] bf16
        const int d = t >> 2, seg = t & 3;
        unsigned r0 = (unsigned)f2bf(L.e.sT[seg*4+0][d]) | ((unsigned)f2bf(L.e.sT[seg*4+1][d]) << 16);
        unsigned r1 = (unsigned)f2bf(L.e.sT[seg*4+2][d]) | ((unsigned)f2bf(L.e.sT[seg*4+3][d]) << 16);
        *(uint2*)(H1T + tbase + (size_t)d * NT + n0 + seg * 4) = make_uint2(r0, r1);
    }
}

// ---------------------------------------------------------------------------
// K2 (layer 2, fused): no score recompute — replay Sg fragments (prefetched),
// stage H1T tiles per wave, 4 agg MFMAs/iter, in-block reduce + epilogue 2.
// ---------------------------------------------------------------------------
union K2LDS {
    struct { unsigned short Ht[WMS][32 * 72]; } m;   // 18432 B
    struct {
        float red[WMS][16][32];
        float sW[32][33], sN[32][33];
        float sH[16][33], sA[16][33];
    } e;                                             // 20864 B
};

__global__ __launch_bounds__(256, 4)
void k2(const float* __restrict__ Hin, const unsigned short* __restrict__ HT,
        const unsigned short* __restrict__ Sg,
        const float* __restrict__ Wsl, const float* __restrict__ Wnl,
        const float* __restrict__ bl, float* __restrict__ out)
{
    __shared__ K2LDS L;
    const int t = threadIdx.x;
    const int w = t >> 6, lane = t & 63;
    const int q = lane >> 4, c = lane & 15;
    const int nb = blockIdx.x, b = blockIdx.y;
    const int n0 = nb * TN;
    const size_t xbase = (size_t)b * NT * DF;
    const size_t tbase = (size_t)b * DF * NT;
    const int mw = w * MROWS;

    const int hrow = lane >> 3, hseg = lane & 7;
    uint4 hv[4];
#pragma unroll
    for (int s = 0; s < 4; ++s)
        hv[s] = *(const uint4*)(HT + tbase + (size_t)(s * 8 + hrow) * NT + mw + hseg * 8);

    const unsigned short* Sp = Sg + (((size_t)b * NBK + nb) * WMS + w) * SG_FRAG
                             + (size_t)lane * 8;
    bf16x8 sf0 = *(const bf16x8*)(Sp);
    bf16x8 sf1 = *(const bf16x8*)(Sp + 512);

    unsigned short* HtW = L.m.Ht[w];
    f32x4 acc0 = {0.f, 0.f, 0.f, 0.f};
    f32x4 acc1 = {0.f, 0.f, 0.f, 0.f};

    for (int it = 0; it < MITERS; ++it) {
        asm volatile("s_waitcnt lgkmcnt(0)" ::: "memory");
#pragma unroll
        for (int s = 0; s < 4; ++s)
            *(uint4*)(HtW + (s * 8 + hrow) * 72 + hseg * 8) = hv[s];
        bf16x8 nsf0, nsf1;
        if (it + 1 < MITERS) {
            const int m1 = mw + (it + 1) * MT;
#pragma unroll
            for (int s = 0; s < 4; ++s)
                hv[s] = *(const uint4*)(HT + tbase + (size_t)(s * 8 + hrow) * NT + m1 + hseg * 8);
            nsf0 = *(const bf16x8*)(Sp + (size_t)(it + 1) * 1024);
            nsf1 = *(const bf16x8*)(Sp + (size_t)(it + 1) * 1024 + 512);
        }
        asm volatile("s_waitcnt lgkmcnt(0)" ::: "memory");

        const bf16x8 h00 = *(const bf16x8*)(HtW + c * 72 + q * 8);
        const bf16x8 h01 = *(const bf16x8*)(HtW + (16 + c) * 72 + q * 8);
        acc0 = __builtin_amdgcn_mfma_f32_16x16x32_bf16(sf0, h00, acc0, 0, 0, 0);
        acc1 = __builtin_amdgcn_mfma_f32_16x16x32_bf16(sf0, h01, acc1, 0, 0, 0);
        const bf16x8 h10 = *(const bf16x8*)(HtW + c * 72 + 32 + q * 8);
        const bf16x8 h11 = *(const bf16x8*)(HtW + (16 + c) * 72 + 32 + q * 8);
        acc0 = __builtin_amdgcn_mfma_f32_16x16x32_bf16(sf1, h10, acc0, 0, 0, 0);
        acc1 = __builtin_amdgcn_mfma_f32_16x16x32_bf16(sf1, h11, acc1, 0, 0, 0);

        if (it + 1 < MITERS) { sf0 = nsf0; sf1 = nsf1; }
    }

    asm volatile("s_waitcnt lgkmcnt(0)" ::: "memory");
    __syncthreads();                       // all waves done with L.m (alias!)

#pragma unroll
    for (int r = 0; r < 4; ++r) {
        L.e.red[w][q * 4 + r][c]      = acc0[r];
        L.e.red[w][q * 4 + r][16 + c] = acc1[r];
    }
    const int row8 = t >> 3, c4 = (t & 7) * 4;
    {
        const float4 wv0 = *(const float4*)(Wsl + row8 * DF + c4);
        const float4 wv1 = *(const float4*)(Wnl + row8 * DF + c4);
        L.e.sW[row8][c4+0]=wv0.x; L.e.sW[row8][c4+1]=wv0.y;
        L.e.sW[row8][c4+2]=wv0.z; L.e.sW[row8][c4+3]=wv0.w;
        L.e.sN[row8][c4+0]=wv1.x; L.e.sN[row8][c4+1]=wv1.y;
        L.e.sN[row8][c4+2]=wv1.z; L.e.sN[row8][c4+3]=wv1.w;
    }
    float4 hvv;
    if (t < 128) {
        hvv = *(const float4*)(Hin + xbase + (size_t)(n0 + row8) * DF + c4);
    }
    __syncthreads();
    if (t < 128) {
        float4 a = *(const float4*)&L.e.red[0][row8][c4];
#pragma unroll
        for (int ww = 1; ww < WMS; ++ww) {
            const float4 p = *(const float4*)&L.e.red[ww][row8][c4];
            a.x += p.x; a.y += p.y; a.z += p.z; a.w += p.w;
        }
        L.e.sA[row8][c4+0]=a.x; L.e.sA[row8][c4+1]=a.y;
        L.e.sA[row8][c4+2]=a.z; L.e.sA[row8][c4+3]=a.w;
        L.e.sH[row8][c4+0]=hvv.x; L.e.sH[row8][c4+1]=hvv.y;
        L.e.sH[row8][c4+2]=hvv.z; L.e.sH[row8][c4+3]=hvv.w;
    }
    __syncthreads();
    if (t < 128) {
        float4 z = make_float4(bl[c4+0], bl[c4+1], bl[c4+2], bl[c4+3]);
#pragma unroll
        for (int k = 0; k < DF; ++k) {
            const float hk = L.e.sH[row8][k], ak = L.e.sA[row8][k];
            z.x += hk * L.e.sW[k][c4+0] + ak * L.e.sN[k][c4+0];
            z.y += hk * L.e.sW[k][c4+1] + ak * L.e.sN[k][c4+1];
            z.z += hk * L.e.sW[k][c4+2] + ak * L.e.sN[k][c4+2];
            z.w += hk * L.e.sW[k][c4+3] + ak * L.e.sN[k][c4+3];
        }
        z.x = z.x > 0.f ? z.x : __expf(z.x) - 1.f;
        z.y = z.y > 0.f ? z.y : __expf(z.y) - 1.f;
        z.z = z.z > 0.f ? z.z : __expf(z.z) - 1.f;
        z.w = z.w > 0.f ? z.w : __expf(z.w) - 1.f;
        *(float4*)(out + xbase + (size_t)(n0 + row8) * DF + c4) = z;
    }
}

extern "C" void kernel_launch(void* const* d_in, const int* in_sizes, int n_in,
                              void* d_out, int out_size, void* d_ws, size_t ws_size,
                              hipStream_t stream) {
    const float* X  = (const float*)d_in[0];
    const float* Ws = (const float*)d_in[1];   // [2][32][32]
    const float* Wn = (const float*)d_in[2];   // [2][32][32]
    const float* bv = (const float*)d_in[3];   // [2][32]
    float* out = (float*)d_out;

    char* ws = (char*)d_ws;
    float* h1 = (float*)ws;                                  // 1,310,720 B
    unsigned short* Xb  = (unsigned short*)(ws + 1310720);   // 655,360 B
    unsigned short* XT  = Xb + (size_t)NB * NT * DF;         // 655,360 B
    unsigned short* H1T = XT + (size_t)NB * NT * DF;         // 655,360 B
    unsigned short* Sg  = H1T + (size_t)NB * NT * DF;        // 52,428,800 B (~55.7 MB total)

    prep<<<320, 256, 0, stream>>>(X, Xb, XT);
    k1<<<dim3(NBK, NB), 256, 0, stream>>>(X, Xb, XT, Ws, Wn, bv, h1, H1T, Sg);
    k2<<<dim3(NBK, NB), 256, 0, stream>>>(h1, H1T, Sg, Ws + DF * DF, Wn + DF * DF,
                                          bv + DF, out);
}

// Round 7
// 99.011 us; speedup vs baseline: 5.0723x; 1.7119x over previous
//
#include <hip/hip_runtime.h>
#include <math.h>

#define NT 2560
#define DF 32
#define NB 4
#define SELF_EPS 0.5f
#define MS 8                 // m-split across blocks
#define MROWS (NT / MS)      // 320 m rows per block
#define MT 64                // m tile
#define MITERS (MROWS / MT)  // 5
#define TN 64                // n rows per block (4 waves x 16)
#define NBK (NT / TN)        // 40 n-blocks

typedef __attribute__((ext_vector_type(8))) short bf16x8;
typedef __attribute__((ext_vector_type(4))) float f32x4;

// hardware packed fp32->bf16 (RNE on gfx950): 1 inst replaces ~11
__device__ __forceinline__ unsigned pk2(float a, float b) {
    unsigned r;
    asm("v_cvt_pk_bf16_f32 %0, %1, %2" : "=v"(r) : "v"(a), "v"(b));
    return r;
}

__device__ __forceinline__ float fast_rcp(float x) {
#if __has_builtin(__builtin_amdgcn_rcpf)
    return __builtin_amdgcn_rcpf(x);
#else
    return 1.0f / x;
#endif
}

// tanh(relu(x)) = 1 - 2/(exp(2x)+1) for x>=0
__device__ __forceinline__ float tanh_relu(float x) {
    x = fmaxf(x, 0.0f);
    float e = __expf(x + x);
    return 1.0f - 2.0f * fast_rcp(e + 1.0f);
}

// ---------------------------------------------------------------------------
// prep: convert X fp32 -> Xb bf16 row-major [B][NT][32] and XT bf16
// transposed [B][32][NT].
// ---------------------------------------------------------------------------
__global__ __launch_bounds__(256, 4)
void prep(const float* __restrict__ X,
          unsigned short* __restrict__ Xb, unsigned short* __restrict__ XT)
{
    const int t = threadIdx.x;
    __shared__ float sT[32][33];
    const int tile = blockIdx.x;
    const int b = tile / 80, n0 = (tile % 80) * 32;
    const int row = t >> 3, c4 = (t & 7) * 4;
    const size_t rbase = ((size_t)(b * NT + n0 + row)) * DF + c4;
    const float4 v = *(const float4*)(X + rbase);
    unsigned p0 = pk2(v.x, v.y);
    unsigned p1 = pk2(v.z, v.w);
    *(uint2*)(Xb + rbase) = make_uint2(p0, p1);
    sT[row][c4 + 0] = v.x; sT[row][c4 + 1] = v.y;
    sT[row][c4 + 2] = v.z; sT[row][c4 + 3] = v.w;
    __syncthreads();
    const int d = t >> 3, nq = (t & 7) * 4;
    unsigned q0 = pk2(sT[nq + 0][d], sT[nq + 1][d]);
    unsigned q1 = pk2(sT[nq + 2][d], sT[nq + 3][d]);
    *(uint2*)(XT + ((size_t)(b * DF + d)) * NT + n0 + nq) = make_uint2(q0, q1);
}

// ---------------------------------------------------------------------------
// main (layer 1): per block, n-tile of 64 rows x m-slice of 320 rows.
// scores via mfma(A=Xm,B=Xn) -> per-wave row-major S in LDS (b64 writes),
// agg via mfma(A=S,B=H^T) accumulated in regs; partials to private P slot.
// The A-layout S fragments read back from LDS are ALSO streamed to Sg
// (bf16, coalesced 16B/lane) so layer 2 can skip all score computation.
// ---------------------------------------------------------------------------
__global__ __launch_bounds__(256, 4)
void gsage_main(const unsigned short* __restrict__ Xb,  // [B][NT][32] bf16
                const unsigned short* __restrict__ HT,  // [B][32][NT] bf16
                float* __restrict__ P,                  // [MS][B][NT][32] fp32
                unsigned short* __restrict__ Sg)        // S-frag stream
{
    __shared__ unsigned short XmL[64 * 40];       // pad 40 (80B rows)
    __shared__ unsigned short HtL[32 * 72];       // pad 72 (144B rows)
    __shared__ unsigned short Ss[4 * 16 * 72];    // per-wave 16n x 64m (pad 72)

    const int t = threadIdx.x;
    const int w = t >> 6, lane = t & 63;
    const int q = lane >> 4, c = lane & 15;
    const int n0 = blockIdx.x * TN;
    const int mbase = blockIdx.y * MROWS;
    const int b = blockIdx.z;

    const size_t xbase = (size_t)b * NT * DF;   // elem offsets (row-major)
    const size_t tbase = (size_t)b * DF * NT;   // elem offsets (transposed)

    // score B-frag: Xn[n = n0+w*16+c][k = q*8 .. q*8+7], constant over m-loop
    const bf16x8 bfn = *(const bf16x8*)(Xb + xbase + (size_t)(n0 + w * 16 + c) * DF + q * 8);

    f32x4 acc0 = {0.f, 0.f, 0.f, 0.f};
    f32x4 acc1 = {0.f, 0.f, 0.f, 0.f};

    const int xrow = t >> 2, xseg = t & 3;   // Xm stage: 64 rows, 4 x 16B
    const int hrow = t >> 3, hseg = t & 7;   // HT stage: 32 rows, 8 x 16B

    uint4 xv = *(const uint4*)(Xb + xbase + (size_t)(mbase + xrow) * DF + xseg * 8);
    uint4 hv = *(const uint4*)(HT + tbase + (size_t)hrow * NT + mbase + hseg * 8);

    const int n_g = n0 + w * 16 + c;
    unsigned short* SsW = Ss + w * (16 * 72);

    // per-(block,wave,lane) S-frag stream base: [b][my][nb][w][it][kc][lane][8]
    unsigned short* Sgw = Sg
        + ((((size_t)b * MS + blockIdx.y) * NBK + blockIdx.x) * 4 + w)
          * ((size_t)MITERS * 2 * 64 * 8)
        + (size_t)lane * 8;

    for (int it = 0; it < MITERS; ++it) {
        const int m0 = mbase + it * MT;
        __syncthreads();                       // prior iter done reading LDS
        *(uint4*)(XmL + xrow * 40 + xseg * 8) = xv;
        *(uint4*)(HtL + hrow * 72 + hseg * 8) = hv;
        if (it + 1 < MITERS) {
            const int m1 = m0 + MT;
            xv = *(const uint4*)(Xb + xbase + (size_t)(m1 + xrow) * DF + xseg * 8);
            hv = *(const uint4*)(HT + tbase + (size_t)hrow * NT + m1 + hseg * 8);
        }
        __syncthreads();                       // tiles staged

        // ---- scores: St[m][n] tiles; lane holds S[n=c][m = t4*16+q*4+r] ----
        if (m0 == n0) {
            #pragma unroll
            for (int t4 = 0; t4 < 4; ++t4) {
                const bf16x8 af = *(const bf16x8*)(XmL + (t4 * 16 + c) * 40 + q * 8);
                const f32x4 zero = {0.f, 0.f, 0.f, 0.f};
                f32x4 st = __builtin_amdgcn_mfma_f32_16x16x32_bf16(af, bfn, zero, 0, 0, 0);
                const int m2 = m0 + t4 * 16 + q * 4;
                float v0 = tanh_relu(st[0]); if (n_g == m2 + 0) v0 += SELF_EPS;
                float v1 = tanh_relu(st[1]); if (n_g == m2 + 1) v1 += SELF_EPS;
                float v2 = tanh_relu(st[2]); if (n_g == m2 + 2) v2 += SELF_EPS;
                float v3 = tanh_relu(st[3]); if (n_g == m2 + 3) v3 += SELF_EPS;
                unsigned p0 = pk2(v0, v1);
                unsigned p1 = pk2(v2, v3);
                *(uint2*)(SsW + c * 72 + t4 * 16 + q * 4) = make_uint2(p0, p1);
            }
        } else {
            #pragma unroll
            for (int t4 = 0; t4 < 4; ++t4) {
                const bf16x8 af = *(const bf16x8*)(XmL + (t4 * 16 + c) * 40 + q * 8);
                const f32x4 zero = {0.f, 0.f, 0.f, 0.f};
                f32x4 st = __builtin_amdgcn_mfma_f32_16x16x32_bf16(af, bfn, zero, 0, 0, 0);
                unsigned p0 = pk2(tanh_relu(st[0]), tanh_relu(st[1]));
                unsigned p1 = pk2(tanh_relu(st[2]), tanh_relu(st[3]));
                *(uint2*)(SsW + c * 72 + t4 * 16 + q * 4) = make_uint2(p0, p1);
            }
        }
        // cross-lane S visibility within the wave: drain LDS writes
        asm volatile("s_waitcnt lgkmcnt(0)" ::: "memory");

        // ---- agg: acc[n][d] += S[n][m] * H[m][d], K=64 in 2 chunks ----
        #pragma unroll
        for (int kc = 0; kc < 2; ++kc) {
            const bf16x8 sf = *(const bf16x8*)(SsW + c * 72 + kc * 32 + q * 8);
            // stream the A-layout fragment out for layer 2 (coalesced 16B/lane)
            *(uint4*)(Sgw + (size_t)(it * 2 + kc) * (64 * 8)) = __builtin_bit_cast(uint4, sf);
            const bf16x8 h0 = *(const bf16x8*)(HtL + c * 72 + kc * 32 + q * 8);
            const bf16x8 h1 = *(const bf16x8*)(HtL + (16 + c) * 72 + kc * 32 + q * 8);
            acc0 = __builtin_amdgcn_mfma_f32_16x16x32_bf16(sf, h0, acc0, 0, 0, 0);
            acc1 = __builtin_amdgcn_mfma_f32_16x16x32_bf16(sf, h1, acc1, 0, 0, 0);
        }
    }

    float* ap = P + ((size_t)blockIdx.y * NB + b) * NT * DF
                  + (size_t)(n0 + w * 16 + q * 4) * DF + c;
    #pragma unroll
    for (int r = 0; r < 4; ++r) {
        ap[(size_t)r * DF] = acc0[r];
        ap[(size_t)r * DF + 16] = acc1[r];
    }
}

// ---------------------------------------------------------------------------
// layer-2 agg: NO score recompute. Stream the stored A-layout S fragments
// (prefetched one iter ahead), stage HT tile, 4 agg MFMAs per iter.
// ---------------------------------------------------------------------------
__global__ __launch_bounds__(256, 6)
void gsage_agg(const unsigned short* __restrict__ Sg,
               const unsigned short* __restrict__ HT,  // [B][32][NT] bf16
               float* __restrict__ P)                  // [MS][B][NT][32] fp32
{
    __shared__ unsigned short HtL[32 * 72];

    const int t = threadIdx.x;
    const int w = t >> 6, lane = t & 63;
    const int q = lane >> 4, c = lane & 15;
    const int n0 = blockIdx.x * TN;
    const int mbase = blockIdx.y * MROWS;
    const int b = blockIdx.z;
    const size_t tbase = (size_t)b * DF * NT;

    const int hrow = t >> 3, hseg = t & 7;
    uint4 hv = *(const uint4*)(HT + tbase + (size_t)hrow * NT + mbase + hseg * 8);

    const unsigned short* Sp = Sg
        + ((((size_t)b * MS + blockIdx.y) * NBK + blockIdx.x) * 4 + w)
          * ((size_t)MITERS * 2 * 64 * 8)
        + (size_t)lane * 8;

    bf16x8 sf0 = *(const bf16x8*)(Sp);
    bf16x8 sf1 = *(const bf16x8*)(Sp + 64 * 8);

    f32x4 acc0 = {0.f, 0.f, 0.f, 0.f};
    f32x4 acc1 = {0.f, 0.f, 0.f, 0.f};

    for (int it = 0; it < MITERS; ++it) {
        __syncthreads();                       // prior iter done reading HtL
        *(uint4*)(HtL + hrow * 72 + hseg * 8) = hv;
        bf16x8 nsf0, nsf1;
        if (it + 1 < MITERS) {
            hv = *(const uint4*)(HT + tbase + (size_t)hrow * NT
                                 + (mbase + (it + 1) * MT) + hseg * 8);
            nsf0 = *(const bf16x8*)(Sp + (size_t)((it + 1) * 2 + 0) * (64 * 8));
            nsf1 = *(const bf16x8*)(Sp + (size_t)((it + 1) * 2 + 1) * (64 * 8));
        }
        __syncthreads();                       // tile staged

        const bf16x8 h00 = *(const bf16x8*)(HtL + c * 72 + 0 * 32 + q * 8);
        const bf16x8 h01 = *(const bf16x8*)(HtL + (16 + c) * 72 + 0 * 32 + q * 8);
        acc0 = __builtin_amdgcn_mfma_f32_16x16x32_bf16(sf0, h00, acc0, 0, 0, 0);
        acc1 = __builtin_amdgcn_mfma_f32_16x16x32_bf16(sf0, h01, acc1, 0, 0, 0);
        const bf16x8 h10 = *(const bf16x8*)(HtL + c * 72 + 1 * 32 + q * 8);
        const bf16x8 h11 = *(const bf16x8*)(HtL + (16 + c) * 72 + 1 * 32 + q * 8);
        acc0 = __builtin_amdgcn_mfma_f32_16x16x32_bf16(sf1, h10, acc0, 0, 0, 0);
        acc1 = __builtin_amdgcn_mfma_f32_16x16x32_bf16(sf1, h11, acc1, 0, 0, 0);

        if (it + 1 < MITERS) { sf0 = nsf0; sf1 = nsf1; }
    }

    float* ap = P + ((size_t)blockIdx.y * NB + b) * NT * DF
                  + (size_t)(n0 + w * 16 + q * 4) * DF + c;
    #pragma unroll
    for (int r = 0; r < 4; ++r) {
        ap[(size_t)r * DF] = acc0[r];
        ap[(size_t)r * DF + 16] = acc1[r];
    }
}

// ---------------------------------------------------------------------------
// epilogue: agg = sum of 8 m-slice partials; Hout = elu(Hin*Ws + agg*Wn + b);
// optionally emit Hout^T bf16.
// ---------------------------------------------------------------------------
__global__ __launch_bounds__(256, 4)
void gsage_epi(const float* __restrict__ Hin, const float* __restrict__ P,
               const float* __restrict__ Wsl, const float* __restrict__ Wnl,
               const float* __restrict__ bl,
               float* __restrict__ Hout, unsigned short* __restrict__ HTout)
{
    __shared__ float sW[32][33], sN[32][33], sH[32][36], sA[32][36], sT[32][33];
    const int t = threadIdx.x;
    const int n0 = blockIdx.x * 32;
    const int b = blockIdx.y;
    const int row = t >> 3, c4 = (t & 7) * 4;
    const size_t rb = ((size_t)(b * NT + n0 + row)) * DF + c4;
    const float4 hv = *(const float4*)(Hin + rb);
    const size_t pstride = (size_t)NB * NT * DF;
    float4 av = *(const float4*)(P + rb);
    #pragma unroll
    for (int s = 1; s < MS; ++s) {
        const float4 pv = *(const float4*)(P + (size_t)s * pstride + rb);
        av.x += pv.x; av.y += pv.y; av.z += pv.z; av.w += pv.w;
    }
    const float4 w0 = *(const float4*)(Wsl + row * DF + c4);
    const float4 w1 = *(const float4*)(Wnl + row * DF + c4);
    sH[row][c4+0]=hv.x; sH[row][c4+1]=hv.y; sH[row][c4+2]=hv.z; sH[row][c4+3]=hv.w;
    sA[row][c4+0]=av.x; sA[row][c4+1]=av.y; sA[row][c4+2]=av.z; sA[row][c4+3]=av.w;
    sW[row][c4+0]=w0.x; sW[row][c4+1]=w0.y; sW[row][c4+2]=w0.z; sW[row][c4+3]=w0.w;
    sN[row][c4+0]=w1.x; sN[row][c4+1]=w1.y; sN[row][c4+2]=w1.z; sN[row][c4+3]=w1.w;
    __syncthreads();

    float4 z = make_float4(bl[c4+0], bl[c4+1], bl[c4+2], bl[c4+3]);
    #pragma unroll
    for (int k = 0; k < DF; ++k) {
        const float hk = sH[row][k], ak = sA[row][k];
        z.x += hk * sW[k][c4+0] + ak * sN[k][c4+0];
        z.y += hk * sW[k][c4+1] + ak * sN[k][c4+1];
        z.z += hk * sW[k][c4+2] + ak * sN[k][c4+2];
        z.w += hk * sW[k][c4+3] + ak * sN[k][c4+3];
    }
    z.x = z.x > 0.f ? z.x : __expf(z.x) - 1.f;
    z.y = z.y > 0.f ? z.y : __expf(z.y) - 1.f;
    z.z = z.z > 0.f ? z.z : __expf(z.z) - 1.f;
    z.w = z.w > 0.f ? z.w : __expf(z.w) - 1.f;
    *(float4*)(Hout + rb) = z;

    if (HTout != nullptr) {
        sT[row][c4+0]=z.x; sT[row][c4+1]=z.y; sT[row][c4+2]=z.z; sT[row][c4+3]=z.w;
        __syncthreads();
        const int d = t >> 3, nq = (t & 7) * 4;
        unsigned q0 = pk2(sT[nq+0][d], sT[nq+1][d]);
        unsigned q1 = pk2(sT[nq+2][d], sT[nq+3][d]);
        *(uint2*)(HTout + ((size_t)(b * DF + d)) * NT + n0 + nq) = make_uint2(q0, q1);
    }
}

extern "C" void kernel_launch(void* const* d_in, const int* in_sizes, int n_in,
                              void* d_out, int out_size, void* d_ws, size_t ws_size,
                              hipStream_t stream) {
    const float* X  = (const float*)d_in[0];
    const float* Ws = (const float*)d_in[1];   // [2][32][32]
    const float* Wn = (const float*)d_in[2];   // [2][32][32]
    const float* bv = (const float*)d_in[3];   // [2][32]
    float* out = (float*)d_out;

    char* ws = (char*)d_ws;
    float* P  = (float*)ws;                                  // 10,485,760 B
    float* h1 = P + (size_t)MS * NB * NT * DF;               // 1,310,720 B
    unsigned short* Xb  = (unsigned short*)(ws + 11796480);  // 655,360 B
    unsigned short* XT  = Xb + (size_t)NB * NT * DF;         // 655,360 B
    unsigned short* H1T = XT + (size_t)NB * NT * DF;         // 655,360 B
    unsigned short* Sg  = H1T + (size_t)NB * NT * DF;        // 52,428,800 B

    prep<<<320, 256, 0, stream>>>(X, Xb, XT);

    dim3 g(NBK, MS, NB);   // 40 x 8 x 4 = 1280 blocks
    gsage_main<<<g, 256, 0, stream>>>(Xb, XT, P, Sg);
    gsage_epi<<<dim3(NT / 32, NB), 256, 0, stream>>>(X, P, Ws, Wn, bv, h1, H1T);
    gsage_agg<<<g, 256, 0, stream>>>(Sg, H1T, P);
    gsage_epi<<<dim3(NT / 32, NB), 256, 0, stream>>>(h1, P, Ws + DF * DF, Wn + DF * DF,
                                                     bv + DF, out, nullptr);
}